// Round 4
// baseline (19428.769 us; speedup 1.0000x reference)
//
#include <hip/hip_runtime.h>
#include <hip/hip_fp16.h>
#include <stdint.h>

#define TT 1024
#define BB 64
#define DHH 256
#define HH 512
#define G3 1536
#define KFAST 24

typedef _Float16 f16;
typedef _Float16 f16x4 __attribute__((ext_vector_type(4)));
typedef _Float16 f16x8 __attribute__((ext_vector_type(8)));
typedef float f32x4 __attribute__((ext_vector_type(4)));
typedef unsigned long long u64;
typedef uint32_t u32;
typedef u32 u32x4 __attribute__((ext_vector_type(4)));

__device__ __forceinline__ float sigm(float x){ return 1.0f/(1.0f+__expf(-x)); }
__device__ __forceinline__ float tanh_f(float x){ return 2.0f/(1.0f+__expf(-2.0f*x)) - 1.0f; }

// ---------------- prep: f32->f16 weights, folded bias ----------------
__global__ void k_prep(const float* __restrict__ wih, const float* __restrict__ whh,
                       const float* __restrict__ bih, const float* __restrict__ bhh,
                       f16* __restrict__ wih_h, f16* __restrict__ whh_h, float* __restrict__ biasf){
  int i = blockIdx.x*256 + threadIdx.x;
  if (i < G3*HH){ wih_h[i] = (f16)wih[i]; whh_h[i] = (f16)whh[i]; }
  // fold b_ih (all gates) + b_hh (r,z gates only; n-gate's b_hh stays inside r*(...))
  if (i < G3) biasf[i] = bih[i] + (i < 2*HH ? bhh[i] : 0.0f);
}

// ---------------- build x = concat(s, p.sum(axis=2)) as f16 [T*B][512] ----------------
__global__ void k_buildx(const float* __restrict__ s, const float* __restrict__ p, f16* __restrict__ x){
  int m = blockIdx.x;             // m = t*64 + b
  int t = m >> 6, b = m & 63;
  int l = threadIdx.x;            // 0..63 -> 4 floats each
  const float4* s4 = reinterpret_cast<const float4*>(s + ((size_t)b*TT + t)*DHH);
  const float4* p4 = reinterpret_cast<const float4*>(p + ((size_t)b*TT + t)*8*DHH);
  float4 sv = s4[l];
  float4 a  = p4[l];
#pragma unroll
  for (int k=1;k<8;k++){ float4 v = p4[k*64 + l]; a.x+=v.x; a.y+=v.y; a.z+=v.z; a.w+=v.w; }
  f16* xr = x + (size_t)m*HH;
  f16x4 hs = { (f16)sv.x,(f16)sv.y,(f16)sv.z,(f16)sv.w };
  f16x4 hp = { (f16)a.x,(f16)a.y,(f16)a.z,(f16)a.w };
  *reinterpret_cast<f16x4*>(xr + l*4)       = hs;
  *reinterpret_cast<f16x4*>(xr + 256 + l*4) = hp;
}

// ---------------- gi GEMM: D[wrow][xrow] = sum_k W_ih[wrow][k] * x[xrow][k]  (+bias) ----------------
// Writes gi in scan-friendly layout: gi[((t*16+ksl)*4+g)*16 + b'][96] f16, 96 = gate*32 + j'
#define LDAP 72
__global__ __launch_bounds__(256) void k_gemm(const f16* __restrict__ x, const f16* __restrict__ w,
                       const float* __restrict__ biasf, f16* __restrict__ gi){
  __shared__ f16 lA[128*LDAP];   // W tile   [128 wrows][64 k] padded
  __shared__ f16 lB[128*LDAP];   // x tile   [128 xrows][64 k] padded
  int by = blockIdx.x;           // wrow tile (12)
  int bx = blockIdx.y;           // xrow tile (512)
  int tid = threadIdx.x, l = tid & 63, wv = tid >> 6;
  int wm = wv >> 1, wn = wv & 1;

  f32x4 acc[4][4];
#pragma unroll
  for (int i=0;i<4;i++)
#pragma unroll
    for (int j=0;j<4;j++) acc[i][j] = (f32x4){0.f,0.f,0.f,0.f};

  for (int kt = 0; kt < 8; ++kt){
#pragma unroll
    for (int r = 0; r < 4; ++r){
      int c = tid + 256*r;            // 1024 chunks of 16B
      int row = c >> 3, o = c & 7;
      f16x8 va = *reinterpret_cast<const f16x8*>(w + (size_t)(by*128+row)*HH + kt*64 + o*8);
      f16x8 vb = *reinterpret_cast<const f16x8*>(x + (size_t)(bx*128+row)*HH + kt*64 + o*8);
      *reinterpret_cast<f16x8*>(&lA[row*LDAP + o*8]) = va;
      *reinterpret_cast<f16x8*>(&lB[row*LDAP + o*8]) = vb;
    }
    __syncthreads();
#pragma unroll
    for (int kk = 0; kk < 2; ++kk){
      f16x8 aF[4], bF[4];
#pragma unroll
      for (int mi=0;mi<4;mi++)
        aF[mi] = *reinterpret_cast<const f16x8*>(&lA[(wm*64+mi*16+(l&15))*LDAP + kk*32 + (l>>4)*8]);
#pragma unroll
      for (int ni=0;ni<4;ni++)
        bF[ni] = *reinterpret_cast<const f16x8*>(&lB[(wn*64+ni*16+(l&15))*LDAP + kk*32 + (l>>4)*8]);
#pragma unroll
      for (int mi=0;mi<4;mi++)
#pragma unroll
        for (int ni=0;ni<4;ni++)
          acc[mi][ni] = __builtin_amdgcn_mfma_f32_16x16x32_f16(aF[mi], bF[ni], acc[mi][ni], 0,0,0);
    }
    __syncthreads();
  }
  // epilogue: D m = (l>>4)*4+reg -> 4 consecutive wrows; n = l&15 -> xrow
#pragma unroll
  for (int mi=0;mi<4;mi++){
    int wrow0 = by*128 + wm*64 + mi*16 + (l>>4)*4;
    float4 bv = *reinterpret_cast<const float4*>(biasf + wrow0);
    int gate = wrow0 >> 9, j = wrow0 & 511, ksl = j >> 5, rp = gate*32 + (j&31);
#pragma unroll
    for (int ni=0;ni<4;ni++){
      int xrow = bx*128 + wn*64 + ni*16 + (l&15);
      int t = xrow >> 6, g = (xrow>>4)&3, bp = xrow & 15;
      size_t dst = ((((size_t)t*16 + ksl)*4 + g)*16 + bp)*96 + rp;
      union { u64 u; f16x4 h; } cv;
      cv.h = (f16x4){ (f16)(acc[mi][ni][0]+bv.x), (f16)(acc[mi][ni][1]+bv.y),
                      (f16)(acc[mi][ni][2]+bv.z), (f16)(acc[mi][ni][3]+bv.w) };
      *reinterpret_cast<u64*>(gi + dst) = cv.u;
    }
  }
}

// ---------------- persistent GRU scan: XCD-local exchange + MALL mirror fallback ----------------
// 256 WGs x 1 wave; active iff (bid&7)<4. Group g = bid&7 lands on XCD g (round-robin
// dispatch heuristic). Within a group, 32 waves exchange h via plain stores + sc0 (L2)
// poll loads. Dual-store to a MALL mirror (relaxed agent atomics) guarantees progress
// if placement differs (correctness never depends on WG->XCD mapping).
struct U64H { union { u64 u; f16x4 h; }; };

__global__ __launch_bounds__(64) void k_scan(const f16* __restrict__ whh_h, const f16* __restrict__ gi,
                      const float* __restrict__ bhh, f16* __restrict__ hh, f16* __restrict__ mir){
  const int bid = blockIdx.x;
  if ((bid & 7) >= 4) return;                        // idle half (XCDs 4..7)
  const int g = bid & 7;                             // batch-group = XCD
  const int role = bid >> 3;                         // 0..31
  const int ksl = role >> 1, wv = role & 1;
  const int l = threadIdx.x;                         // 0..63
  const int lm = l & 15, lh = l >> 4;

  // persistent A-fragments: aW[gate][kt], W row = gate*512 + ksl*32 + wv*16 + lm, k = kt*32 + lh*8
  f16x8 aW[3][16];
#pragma unroll
  for (int gate = 0; gate < 3; ++gate){
    const f16* wr = whh_h + ((size_t)gate*512 + ksl*32 + wv*16 + lm)*HH + lh*8;
#pragma unroll
    for (int kt = 0; kt < 16; ++kt)
      aW[gate][kt] = *reinterpret_cast<const f16x8*>(wr + kt*32);
  }
  const int jl    = wv*16 + lh*4;                    // first of 4 j-locals this lane owns
  const int jglob = ksl*32 + jl;
  float4 bnv = *reinterpret_cast<const float4*>(bhh + 2*HH + jglob);   // b_hh n-gate
  float bna[4] = {bnv.x, bnv.y, bnv.z, bnv.w};
  const int bp = lm, bglob = g*16 + bp;

  U64H cA[3], cB[3], ho, hn;
  ho.u = 0ull;

  // ---- t = 0 peel: h_{-1} = 0, no poll; prefetch gi(1) into cB ----
  {
    const f16* g0 = gi + ((((size_t)0*16 + ksl)*4 + g)*16 + bp)*96;
    cA[0].u = *reinterpret_cast<const u64*>(g0 + jl);
    cA[1].u = *reinterpret_cast<const u64*>(g0 + 32 + jl);
    cA[2].u = *reinterpret_cast<const u64*>(g0 + 64 + jl);
    const f16* g1 = gi + ((((size_t)1*16 + ksl)*4 + g)*16 + bp)*96;
    cB[0].u = *reinterpret_cast<const u64*>(g1 + jl);
    cB[1].u = *reinterpret_cast<const u64*>(g1 + 32 + jl);
    cB[2].u = *reinterpret_cast<const u64*>(g1 + 64 + jl);
#pragma unroll
    for (int r = 0; r < 4; ++r){
      float rg = sigm((float)cA[0].h[r]);
      float zg = sigm((float)cA[1].h[r]);
      float ng = tanh_f((float)cA[2].h[r] + rg*bna[r]);
      hn.h[r] = (f16)((1.0f - zg)*ng);
    }
    ho.u = hn.u;
    *reinterpret_cast<u64*>(hh + ((size_t)0*BB + bglob)*HH + jglob) = hn.u;          // fast (L2)
    __hip_atomic_store(reinterpret_cast<u64*>(mir + ((size_t)0*BB + bglob)*HH + jglob), hn.u,
                       __ATOMIC_RELAXED, __HIP_MEMORY_SCOPE_AGENT);                  // mirror (MALL)
  }

#define BODY(T, CUR, NXT, DO_NXT)                                                                    \
  {                                                                                                  \
    const int t_ = (T);                                                                              \
    const f16* hbase = hh + ((size_t)(t_-1)*BB + g*16 + bp)*HH + lh*8;                               \
    u32x4 q[16];                                                                                     \
    int got = 0;                                                                                     \
    for (int att = 0; att < KFAST && !got; ++att){                                                   \
      asm volatile(                                                                                  \
        "global_load_dwordx4 %0, %16, off sc0\n\t"                                                   \
        "global_load_dwordx4 %1, %16, off offset:64 sc0\n\t"                                         \
        "global_load_dwordx4 %2, %16, off offset:128 sc0\n\t"                                        \
        "global_load_dwordx4 %3, %16, off offset:192 sc0\n\t"                                        \
        "global_load_dwordx4 %4, %16, off offset:256 sc0\n\t"                                        \
        "global_load_dwordx4 %5, %16, off offset:320 sc0\n\t"                                        \
        "global_load_dwordx4 %6, %16, off offset:384 sc0\n\t"                                        \
        "global_load_dwordx4 %7, %16, off offset:448 sc0\n\t"                                        \
        "global_load_dwordx4 %8, %16, off offset:512 sc0\n\t"                                        \
        "global_load_dwordx4 %9, %16, off offset:576 sc0\n\t"                                        \
        "global_load_dwordx4 %10, %16, off offset:640 sc0\n\t"                                       \
        "global_load_dwordx4 %11, %16, off offset:704 sc0\n\t"                                       \
        "global_load_dwordx4 %12, %16, off offset:768 sc0\n\t"                                       \
        "global_load_dwordx4 %13, %16, off offset:832 sc0\n\t"                                       \
        "global_load_dwordx4 %14, %16, off offset:896 sc0\n\t"                                       \
        "global_load_dwordx4 %15, %16, off offset:960 sc0\n\t"                                       \
        "s_waitcnt vmcnt(0)"                                                                         \
        : "=&v"(q[0]),"=&v"(q[1]),"=&v"(q[2]),"=&v"(q[3]),                                           \
          "=&v"(q[4]),"=&v"(q[5]),"=&v"(q[6]),"=&v"(q[7]),                                           \
          "=&v"(q[8]),"=&v"(q[9]),"=&v"(q[10]),"=&v"(q[11]),                                         \
          "=&v"(q[12]),"=&v"(q[13]),"=&v"(q[14]),"=&v"(q[15])                                        \
        : "v"(hbase) : "memory");                                                                    \
      int ok = 1;                                                                                    \
      _Pragma("unroll")                                                                              \
      for (int kt = 0; kt < 16; ++kt)                                                                \
        ok &= (int)(q[kt][0] != 0xFFFFFFFFu) & (int)(q[kt][2] != 0xFFFFFFFFu);                       \
      got = __all(ok);                                                                               \
    }                                                                                                \
    f16x8 bF[16];                                                                                    \
    if (got){                                                                                        \
      _Pragma("unroll")                                                                              \
      for (int kt = 0; kt < 16; ++kt) bF[kt] = __builtin_bit_cast(f16x8, q[kt]);                     \
    } else {                                                                                         \
      const u64* ms = reinterpret_cast<const u64*>(mir + ((size_t)(t_-1)*BB + g*16 + bp)*HH + lh*8); \
      union BC { u64 qq[2]; f16x8 v8; } bb[16];                                                      \
      int ok2;                                                                                       \
      do {                                                                                           \
        ok2 = 1;                                                                                     \
        _Pragma("unroll")                                                                            \
        for (int kt = 0; kt < 16; ++kt){                                                             \
          bb[kt].qq[0] = __hip_atomic_load(ms + kt*8,   __ATOMIC_RELAXED, __HIP_MEMORY_SCOPE_AGENT); \
          bb[kt].qq[1] = __hip_atomic_load(ms + kt*8+1, __ATOMIC_RELAXED, __HIP_MEMORY_SCOPE_AGENT); \
          ok2 &= (int)((unsigned)bb[kt].qq[0] != 0xFFFFFFFFu);                                       \
          ok2 &= (int)((unsigned)bb[kt].qq[1] != 0xFFFFFFFFu);                                       \
        }                                                                                            \
      } while (!__all(ok2));                                                                         \
      _Pragma("unroll")                                                                              \
      for (int kt = 0; kt < 16; ++kt) bF[kt] = bb[kt].v8;                                            \
    }                                                                                                \
    if (DO_NXT){                                                                                     \
      const int tn_ = (t_+1 < TT) ? t_+1 : t_;                                                       \
      const f16* gn = gi + ((((size_t)tn_*16 + ksl)*4 + g)*16 + bp)*96;                              \
      NXT[0].u = *reinterpret_cast<const u64*>(gn + jl);                                             \
      NXT[1].u = *reinterpret_cast<const u64*>(gn + 32 + jl);                                        \
      NXT[2].u = *reinterpret_cast<const u64*>(gn + 64 + jl);                                        \
    }                                                                                                \
    f32x4 aR = (f32x4){0.f,0.f,0.f,0.f};                                                             \
    f32x4 aZ = (f32x4){0.f,0.f,0.f,0.f};                                                             \
    f32x4 aN = (f32x4){0.f,0.f,0.f,0.f};                                                             \
    _Pragma("unroll")                                                                                \
    for (int kt = 0; kt < 16; ++kt){                                                                 \
      aR = __builtin_amdgcn_mfma_f32_16x16x32_f16(aW[0][kt], bF[kt], aR, 0,0,0);                     \
      aZ = __builtin_amdgcn_mfma_f32_16x16x32_f16(aW[1][kt], bF[kt], aZ, 0,0,0);                     \
      aN = __builtin_amdgcn_mfma_f32_16x16x32_f16(aW[2][kt], bF[kt], aN, 0,0,0);                     \
    }                                                                                                \
    _Pragma("unroll")                                                                                \
    for (int r = 0; r < 4; ++r){                                                                     \
      float rg = sigm((float)CUR[0].h[r] + aR[r]);                                                   \
      float zg = sigm((float)CUR[1].h[r] + aZ[r]);                                                   \
      float ng = tanh_f((float)CUR[2].h[r] + rg*(aN[r] + bna[r]));                                   \
      hn.h[r] = (f16)((1.0f - zg)*ng + zg*(float)ho.h[r]);                                           \
    }                                                                                                \
    ho.u = hn.u;                                                                                     \
    *reinterpret_cast<u64*>(hh + ((size_t)t_*BB + bglob)*HH + jglob) = hn.u;                         \
    __hip_atomic_store(reinterpret_cast<u64*>(mir + ((size_t)t_*BB + bglob)*HH + jglob), hn.u,       \
                       __ATOMIC_RELAXED, __HIP_MEMORY_SCOPE_AGENT);                                  \
  }

  for (int t = 1; t < TT-1; t += 2){
    BODY(t,   cB, cA, 1)
    BODY(t+1, cA, cB, 1)
  }
  BODY(TT-1, cB, cA, 0)
#undef BODY
}

// ---------------- rewards = sigmoid(h @ W_t + b_t) ----------------
__global__ void k_reward(const f16* __restrict__ hh, const float* __restrict__ wt,
                         const float* __restrict__ bt, float* __restrict__ out){
  int wv = threadIdx.x >> 6, l = threadIdx.x & 63;
  int idx = blockIdx.x*4 + wv;          // idx = b*1024 + t (output order [B][T])
  int b = idx >> 10, t = idx & 1023;
  const f16* hr = hh + ((size_t)t*64 + b)*HH;
  f16x8 hv = *reinterpret_cast<const f16x8*>(hr + l*8);
  float4 w0 = *reinterpret_cast<const float4*>(wt + l*8);
  float4 w1 = *reinterpret_cast<const float4*>(wt + l*8 + 4);
  float sum = (float)hv[0]*w0.x + (float)hv[1]*w0.y + (float)hv[2]*w0.z + (float)hv[3]*w0.w
            + (float)hv[4]*w1.x + (float)hv[5]*w1.y + (float)hv[6]*w1.z + (float)hv[7]*w1.w;
#pragma unroll
  for (int m=32;m>=1;m>>=1) sum += __shfl_xor(sum, m);
  if (l==0) out[idx] = sigm(sum + bt[0]);
}

extern "C" void kernel_launch(void* const* d_in, const int* in_sizes, int n_in,
                              void* d_out, int out_size, void* d_ws, size_t ws_size,
                              hipStream_t stream) {
  const float* s   = (const float*)d_in[0];
  const float* p   = (const float*)d_in[1];
  const float* wih = (const float*)d_in[2];
  const float* whh = (const float*)d_in[3];
  const float* bih = (const float*)d_in[4];
  const float* bhh = (const float*)d_in[5];
  const float* wt  = (const float*)d_in[6];
  const float* bt  = (const float*)d_in[7];
  float* out = (float*)d_out;

  char* ws = (char*)d_ws;
  size_t o = 0;
  auto take = [&](size_t bytes)->char*{ char* r = ws + o; o = (o + bytes + 255) & ~(size_t)255; return r; };
  f16*      x_h   = (f16*)   take((size_t)TT*BB*HH*2);       // 67 MB; reused as hh after k_gemm
  f16*      wih_h = (f16*)   take((size_t)G3*HH*2);
  f16*      whh_h = (f16*)   take((size_t)G3*HH*2);
  float*    biasf = (float*) take((size_t)G3*4);
  f16*      gi_s  = (f16*)   take((size_t)TT*BB*G3*2);       // 201 MB
  f16*      mir   = (f16*)   take((size_t)TT*BB*HH*2);       // 67 MB MALL mirror
  f16*      hh    = x_h;                                     // alias (x dead after k_gemm)
  (void)ws_size; (void)in_sizes; (void)n_in; (void)out_size;

  k_prep  <<<3072, 256, 0, stream>>>(wih, whh, bih, bhh, wih_h, whh_h, biasf);
  k_buildx<<<TT*BB, 64, 0, stream>>>(s, p, x_h);
  k_gemm  <<<dim3(12, 512), 256, 0, stream>>>(x_h, wih_h, biasf, gi_s);
  hipMemsetAsync(hh,  0xFF, (size_t)TT*BB*HH*2, stream);     // poison fast buffer (after gemm reads x)
  hipMemsetAsync(mir, 0xFF, (size_t)TT*BB*HH*2, stream);     // poison mirror
  k_scan  <<<256, 64, 0, stream>>>(whh_h, gi_s, bhh, hh, mir);
  k_reward<<<TT*BB/4, 256, 0, stream>>>(hh, wt, bt, out);
}

// Round 5
// 4452.374 us; speedup vs baseline: 4.3637x; 4.3637x over previous
//
#include <hip/hip_runtime.h>
#include <hip/hip_fp16.h>
#include <stdint.h>

#define TT 1024
#define BB 64
#define DHH 256
#define HH 512
#define G3 1536

typedef _Float16 f16;
typedef _Float16 f16x4 __attribute__((ext_vector_type(4)));
typedef _Float16 f16x8 __attribute__((ext_vector_type(8)));
typedef float f32x4 __attribute__((ext_vector_type(4)));
typedef unsigned long long u64;

__device__ __forceinline__ float sigm(float x){ return 1.0f/(1.0f+__expf(-x)); }
__device__ __forceinline__ float tanh_f(float x){ return 2.0f/(1.0f+__expf(-2.0f*x)) - 1.0f; }

// ---------------- prep: f32->f16 weights, folded bias ----------------
__global__ void k_prep(const float* __restrict__ wih, const float* __restrict__ whh,
                       const float* __restrict__ bih, const float* __restrict__ bhh,
                       f16* __restrict__ wih_h, f16* __restrict__ whh_h, float* __restrict__ biasf){
  int i = blockIdx.x*256 + threadIdx.x;
  if (i < G3*HH){ wih_h[i] = (f16)wih[i]; whh_h[i] = (f16)whh[i]; }
  // fold b_ih (all gates) + b_hh (r,z gates only; n-gate's b_hh stays inside r*(...))
  if (i < G3) biasf[i] = bih[i] + (i < 2*HH ? bhh[i] : 0.0f);
}

// ---------------- build x = concat(s, p.sum(axis=2)) as f16 [T*B][512] ----------------
__global__ void k_buildx(const float* __restrict__ s, const float* __restrict__ p, f16* __restrict__ x){
  int m = blockIdx.x;             // m = t*64 + b
  int t = m >> 6, b = m & 63;
  int l = threadIdx.x;            // 0..63 -> 4 floats each
  const float4* s4 = reinterpret_cast<const float4*>(s + ((size_t)b*TT + t)*DHH);
  const float4* p4 = reinterpret_cast<const float4*>(p + ((size_t)b*TT + t)*8*DHH);
  float4 sv = s4[l];
  float4 a  = p4[l];
#pragma unroll
  for (int k=1;k<8;k++){ float4 v = p4[k*64 + l]; a.x+=v.x; a.y+=v.y; a.z+=v.z; a.w+=v.w; }
  f16* xr = x + (size_t)m*HH;
  f16x4 hs = { (f16)sv.x,(f16)sv.y,(f16)sv.z,(f16)sv.w };
  f16x4 hp = { (f16)a.x,(f16)a.y,(f16)a.z,(f16)a.w };
  *reinterpret_cast<f16x4*>(xr + l*4)       = hs;
  *reinterpret_cast<f16x4*>(xr + 256 + l*4) = hp;
}

// ---------------- gi GEMM: D[wrow][xrow] = sum_k W_ih[wrow][k] * x[xrow][k]  (+bias) ----------------
// Writes gi in scan-friendly layout: gi[((t*16+ksl)*4+g)*16 + b'][96] f16, 96 = gate*32 + j'
#define LDAP 72
__global__ __launch_bounds__(256) void k_gemm(const f16* __restrict__ x, const f16* __restrict__ w,
                       const float* __restrict__ biasf, f16* __restrict__ gi){
  __shared__ f16 lA[128*LDAP];   // W tile   [128 wrows][64 k] padded
  __shared__ f16 lB[128*LDAP];   // x tile   [128 xrows][64 k] padded
  int by = blockIdx.x;           // wrow tile (12)
  int bx = blockIdx.y;           // xrow tile (512)
  int tid = threadIdx.x, l = tid & 63, wv = tid >> 6;
  int wm = wv >> 1, wn = wv & 1;

  f32x4 acc[4][4];
#pragma unroll
  for (int i=0;i<4;i++)
#pragma unroll
    for (int j=0;j<4;j++) acc[i][j] = (f32x4){0.f,0.f,0.f,0.f};

  for (int kt = 0; kt < 8; ++kt){
#pragma unroll
    for (int r = 0; r < 4; ++r){
      int c = tid + 256*r;            // 1024 chunks of 16B
      int row = c >> 3, o = c & 7;
      f16x8 va = *reinterpret_cast<const f16x8*>(w + (size_t)(by*128+row)*HH + kt*64 + o*8);
      f16x8 vb = *reinterpret_cast<const f16x8*>(x + (size_t)(bx*128+row)*HH + kt*64 + o*8);
      *reinterpret_cast<f16x8*>(&lA[row*LDAP + o*8]) = va;
      *reinterpret_cast<f16x8*>(&lB[row*LDAP + o*8]) = vb;
    }
    __syncthreads();
#pragma unroll
    for (int kk = 0; kk < 2; ++kk){
      f16x8 aF[4], bF[4];
#pragma unroll
      for (int mi=0;mi<4;mi++)
        aF[mi] = *reinterpret_cast<const f16x8*>(&lA[(wm*64+mi*16+(l&15))*LDAP + kk*32 + (l>>4)*8]);
#pragma unroll
      for (int ni=0;ni<4;ni++)
        bF[ni] = *reinterpret_cast<const f16x8*>(&lB[(wn*64+ni*16+(l&15))*LDAP + kk*32 + (l>>4)*8]);
#pragma unroll
      for (int mi=0;mi<4;mi++)
#pragma unroll
        for (int ni=0;ni<4;ni++)
          acc[mi][ni] = __builtin_amdgcn_mfma_f32_16x16x32_f16(aF[mi], bF[ni], acc[mi][ni], 0,0,0);
    }
    __syncthreads();
  }
  // epilogue: D m = (l>>4)*4+reg -> 4 consecutive wrows; n = l&15 -> xrow
#pragma unroll
  for (int mi=0;mi<4;mi++){
    int wrow0 = by*128 + wm*64 + mi*16 + (l>>4)*4;
    float4 bv = *reinterpret_cast<const float4*>(biasf + wrow0);
    int gate = wrow0 >> 9, j = wrow0 & 511, ksl = j >> 5, rp = gate*32 + (j&31);
#pragma unroll
    for (int ni=0;ni<4;ni++){
      int xrow = bx*128 + wn*64 + ni*16 + (l&15);
      int t = xrow >> 6, g = (xrow>>4)&3, bp = xrow & 15;
      size_t dst = ((((size_t)t*16 + ksl)*4 + g)*16 + bp)*96 + rp;
      union { u64 u; f16x4 h; } cv;
      cv.h = (f16x4){ (f16)(acc[mi][ni][0]+bv.x), (f16)(acc[mi][ni][1]+bv.y),
                      (f16)(acc[mi][ni][2]+bv.z), (f16)(acc[mi][ni][3]+bv.w) };
      *reinterpret_cast<u64*>(gi + dst) = cv.u;
    }
  }
}

// ---------------- persistent GRU scan: poll-the-data protocol ----------------
// 128 single-wave WGs = 4 batch-groups (16 batches) x 16 j-slices x 2 wave-halves.
// W_hh slice in 192 VGPRs (launch_bounds(64,1) -> 512-VGPR budget so aW is truly
// register-resident; at default bounds the compiler rematerializes ~96 W loads/step).
// hh pre-poisoned to 0xFF; producer = ONE relaxed agent atomic u64 store per lane per
// step; consumer polls the data itself (poison check; computed h is finite so the
// 0xFFFF f16 NaN pattern is unreachable). gi software-pipelined TWO steps ahead.
__global__ __launch_bounds__(64, 1) void k_scan(const f16* __restrict__ whh_h, const f16* __restrict__ gi,
                      const float* __restrict__ bhh, f16* __restrict__ hh){
  const int bid = blockIdx.x;                       // 0..127
  const int g = bid & 3, ksl = (bid >> 2) & 15, wv = bid >> 6;
  const int l = threadIdx.x;                        // 0..63
  const int lm = l & 15, lh = l >> 4;

  // persistent A-fragments: aW[gate][kt], W row = gate*512 + ksl*32 + wv*16 + lm, k = kt*32 + lh*8
  f16x8 aW[3][16];
#pragma unroll
  for (int gate = 0; gate < 3; ++gate){
    const f16* wr = whh_h + ((size_t)gate*512 + ksl*32 + wv*16 + lm)*HH + lh*8;
#pragma unroll
    for (int kt = 0; kt < 16; ++kt)
      aW[gate][kt] = *reinterpret_cast<const f16x8*>(wr + kt*32);
  }
  const int jl    = wv*16 + lh*4;                   // first of 4 j-locals this lane owns
  const int jglob = ksl*32 + jl;
  float4 bnv = *reinterpret_cast<const float4*>(bhh + 2*HH + jglob);   // b_hh n-gate
  float bna[4] = {bnv.x, bnv.y, bnv.z, bnv.w};
  const int bp = lm, bglob = g*16 + bp;

  union U64H { u64 u; f16x4 h; };
  U64H cA[3], cB[3], cC[3], ho, hn;
  ho.u = 0ull;

  // ---- t = 0 peel: h_{-1} = 0, no poll; prefetch gi(1)->cB, gi(2)->cC ----
  {
    const f16* g0 = gi + ((((size_t)0*16 + ksl)*4 + g)*16 + bp)*96;
    cA[0].u = *reinterpret_cast<const u64*>(g0 + jl);
    cA[1].u = *reinterpret_cast<const u64*>(g0 + 32 + jl);
    cA[2].u = *reinterpret_cast<const u64*>(g0 + 64 + jl);
    const f16* g1 = gi + ((((size_t)1*16 + ksl)*4 + g)*16 + bp)*96;
    cB[0].u = *reinterpret_cast<const u64*>(g1 + jl);
    cB[1].u = *reinterpret_cast<const u64*>(g1 + 32 + jl);
    cB[2].u = *reinterpret_cast<const u64*>(g1 + 64 + jl);
    const f16* g2 = gi + ((((size_t)2*16 + ksl)*4 + g)*16 + bp)*96;
    cC[0].u = *reinterpret_cast<const u64*>(g2 + jl);
    cC[1].u = *reinterpret_cast<const u64*>(g2 + 32 + jl);
    cC[2].u = *reinterpret_cast<const u64*>(g2 + 64 + jl);
#pragma unroll
    for (int r = 0; r < 4; ++r){
      float rg = sigm((float)cA[0].h[r]);
      float zg = sigm((float)cA[1].h[r]);
      float ng = tanh_f((float)cA[2].h[r] + rg*bna[r]);
      hn.h[r] = (f16)((1.0f - zg)*ng);
    }
    ho.u = hn.u;
    __hip_atomic_store(reinterpret_cast<u64*>(hh + ((size_t)0*BB + bglob)*HH + jglob), hn.u,
                       __ATOMIC_RELAXED, __HIP_MEMORY_SCOPE_AGENT);
  }

  // BODY(T): consume CUR = gi(T); prefetch gi(T+2) into NXT2 (the buffer freed at T-1).
#define BODY(T, CUR, NXT2)                                                                           \
  {                                                                                                  \
    const int t_ = (T);                                                                              \
    /* issue gi(t+2) BEFORE the poll: independent loads, latency hidden across ~2 steps */           \
    {                                                                                                \
      const int tn_ = (t_+2 < TT) ? t_+2 : TT-1;                                                     \
      const f16* gn = gi + ((((size_t)tn_*16 + ksl)*4 + g)*16 + bp)*96;                              \
      NXT2[0].u = *reinterpret_cast<const u64*>(gn + jl);                                            \
      NXT2[1].u = *reinterpret_cast<const u64*>(gn + 32 + jl);                                       \
      NXT2[2].u = *reinterpret_cast<const u64*>(gn + 64 + jl);                                       \
    }                                                                                                \
    union BC { u64 q[2]; f16x8 v8; } bF[16];                                                         \
    const u64* hsrc = reinterpret_cast<const u64*>(                                                  \
        hh + ((size_t)(t_-1)*BB + g*16 + bp)*HH + lh*8);                                             \
    int ok;                                                                                          \
    do {                                                                                             \
      ok = 1;                                                                                        \
      _Pragma("unroll")                                                                              \
      for (int kt = 0; kt < 16; ++kt){                                                               \
        bF[kt].q[0] = __hip_atomic_load(hsrc + kt*8,   __ATOMIC_RELAXED, __HIP_MEMORY_SCOPE_AGENT);  \
        bF[kt].q[1] = __hip_atomic_load(hsrc + kt*8+1, __ATOMIC_RELAXED, __HIP_MEMORY_SCOPE_AGENT);  \
        ok &= ((unsigned)bF[kt].q[0] != 0xFFFFFFFFu);                                                \
        ok &= ((unsigned)bF[kt].q[1] != 0xFFFFFFFFu);                                                \
      }                                                                                              \
    } while (!__all(ok));                                                                            \
    f32x4 aR = (f32x4){0.f,0.f,0.f,0.f};                                                             \
    f32x4 aZ = (f32x4){0.f,0.f,0.f,0.f};                                                             \
    f32x4 aN = (f32x4){0.f,0.f,0.f,0.f};                                                             \
    _Pragma("unroll")                                                                                \
    for (int kt = 0; kt < 16; ++kt){                                                                 \
      aR = __builtin_amdgcn_mfma_f32_16x16x32_f16(aW[0][kt], bF[kt].v8, aR, 0,0,0);                  \
      aZ = __builtin_amdgcn_mfma_f32_16x16x32_f16(aW[1][kt], bF[kt].v8, aZ, 0,0,0);                  \
      aN = __builtin_amdgcn_mfma_f32_16x16x32_f16(aW[2][kt], bF[kt].v8, aN, 0,0,0);                  \
    }                                                                                                \
    _Pragma("unroll")                                                                                \
    for (int r = 0; r < 4; ++r){                                                                     \
      float rg = sigm((float)CUR[0].h[r] + aR[r]);                                                   \
      float zg = sigm((float)CUR[1].h[r] + aZ[r]);                                                   \
      float ng = tanh_f((float)CUR[2].h[r] + rg*(aN[r] + bna[r]));                                   \
      hn.h[r] = (f16)((1.0f - zg)*ng + zg*(float)ho.h[r]);                                           \
    }                                                                                                \
    ho.u = hn.u;                                                                                     \
    __hip_atomic_store(reinterpret_cast<u64*>(hh + ((size_t)t_*BB + bglob)*HH + jglob), hn.u,        \
                       __ATOMIC_RELAXED, __HIP_MEMORY_SCOPE_AGENT);                                  \
  }

  // t = 1..1023 in 341 triples with 3-buffer rotation (consume B,C,A; refill freed buf)
  for (int t = 1; t < TT; t += 3){
    BODY(t,   cB, cA)
    BODY(t+1, cC, cB)
    BODY(t+2, cA, cC)
  }
#undef BODY
}

// ---------------- rewards = sigmoid(h @ W_t + b_t) ----------------
__global__ void k_reward(const f16* __restrict__ hh, const float* __restrict__ wt,
                         const float* __restrict__ bt, float* __restrict__ out){
  int wv = threadIdx.x >> 6, l = threadIdx.x & 63;
  int idx = blockIdx.x*4 + wv;          // idx = b*1024 + t (output order [B][T])
  int b = idx >> 10, t = idx & 1023;
  const f16* hr = hh + ((size_t)t*64 + b)*HH;
  f16x8 hv = *reinterpret_cast<const f16x8*>(hr + l*8);
  float4 w0 = *reinterpret_cast<const float4*>(wt + l*8);
  float4 w1 = *reinterpret_cast<const float4*>(wt + l*8 + 4);
  float sum = (float)hv[0]*w0.x + (float)hv[1]*w0.y + (float)hv[2]*w0.z + (float)hv[3]*w0.w
            + (float)hv[4]*w1.x + (float)hv[5]*w1.y + (float)hv[6]*w1.z + (float)hv[7]*w1.w;
#pragma unroll
  for (int m=32;m>=1;m>>=1) sum += __shfl_xor(sum, m);
  if (l==0) out[idx] = sigm(sum + bt[0]);
}

extern "C" void kernel_launch(void* const* d_in, const int* in_sizes, int n_in,
                              void* d_out, int out_size, void* d_ws, size_t ws_size,
                              hipStream_t stream) {
  const float* s   = (const float*)d_in[0];
  const float* p   = (const float*)d_in[1];
  const float* wih = (const float*)d_in[2];
  const float* whh = (const float*)d_in[3];
  const float* bih = (const float*)d_in[4];
  const float* bhh = (const float*)d_in[5];
  const float* wt  = (const float*)d_in[6];
  const float* bt  = (const float*)d_in[7];
  float* out = (float*)d_out;

  char* ws = (char*)d_ws;
  size_t o = 0;
  auto take = [&](size_t bytes)->char*{ char* r = ws + o; o = (o + bytes + 255) & ~(size_t)255; return r; };
  f16*      x_h   = (f16*)   take((size_t)TT*BB*HH*2);       // 67 MB
  f16*      wih_h = (f16*)   take((size_t)G3*HH*2);
  f16*      whh_h = (f16*)   take((size_t)G3*HH*2);
  float*    biasf = (float*) take((size_t)G3*4);
  f16*      gi_s  = (f16*)   take((size_t)TT*BB*G3*2);       // 201 MB
  f16*      hh    = (f16*)   take((size_t)TT*BB*HH*2);       // 67 MB
  (void)ws_size; (void)in_sizes; (void)n_in; (void)out_size;

  hipMemsetAsync(hh, 0xFF, (size_t)TT*BB*HH*2, stream);      // poison: poll-the-data sentinel
  k_prep  <<<3072, 256, 0, stream>>>(wih, whh, bih, bhh, wih_h, whh_h, biasf);
  k_buildx<<<TT*BB, 64, 0, stream>>>(s, p, x_h);
  k_gemm  <<<dim3(12, 512), 256, 0, stream>>>(x_h, wih_h, biasf, gi_s);
  k_scan  <<<128, 64, 0, stream>>>(whh_h, gi_s, bhh, hh);
  k_reward<<<TT*BB/4, 256, 0, stream>>>(hh, wt, bt, out);
}

// Round 7
// 2851.998 us; speedup vs baseline: 6.8123x; 1.5611x over previous
//
#include <hip/hip_runtime.h>
#include <hip/hip_fp16.h>
#include <stdint.h>

#define TT 1024
#define BB 64
#define DHH 256
#define HH 512
#define G3 1536
#define CHK 256   // f16 elements per (g,jsl) exchange chunk: [16 batches][16 j] — ONE constant, used by store/poll/reader

typedef _Float16 f16;
typedef _Float16 f16x4 __attribute__((ext_vector_type(4)));
typedef _Float16 f16x8 __attribute__((ext_vector_type(8)));
typedef float f32x4 __attribute__((ext_vector_type(4)));
typedef unsigned long long u64;

__device__ __forceinline__ float sigm(float x){ return 1.0f/(1.0f+__expf(-x)); }
__device__ __forceinline__ float tanh_f(float x){ return 2.0f/(1.0f+__expf(-2.0f*x)) - 1.0f; }

// ---------------- prep: f32->f16 weights, folded bias ----------------
__global__ void k_prep(const float* __restrict__ wih, const float* __restrict__ whh,
                       const float* __restrict__ bih, const float* __restrict__ bhh,
                       f16* __restrict__ wih_h, f16* __restrict__ whh_h, float* __restrict__ biasf){
  int i = blockIdx.x*256 + threadIdx.x;
  if (i < G3*HH){ wih_h[i] = (f16)wih[i]; whh_h[i] = (f16)whh[i]; }
  // fold b_ih (all gates) + b_hh (r,z gates only; n-gate's b_hh stays inside r*(...))
  if (i < G3) biasf[i] = bih[i] + (i < 2*HH ? bhh[i] : 0.0f);
}

// ---------------- build x = concat(s, p.sum(axis=2)) as f16 [T*B][512] ----------------
__global__ void k_buildx(const float* __restrict__ s, const float* __restrict__ p, f16* __restrict__ x){
  int m = blockIdx.x;             // m = t*64 + b
  int t = m >> 6, b = m & 63;
  int l = threadIdx.x;            // 0..63 -> 4 floats each
  const float4* s4 = reinterpret_cast<const float4*>(s + ((size_t)b*TT + t)*DHH);
  const float4* p4 = reinterpret_cast<const float4*>(p + ((size_t)b*TT + t)*8*DHH);
  float4 sv = s4[l];
  float4 a  = p4[l];
#pragma unroll
  for (int k=1;k<8;k++){ float4 v = p4[k*64 + l]; a.x+=v.x; a.y+=v.y; a.z+=v.z; a.w+=v.w; }
  f16* xr = x + (size_t)m*HH;
  f16x4 hs = { (f16)sv.x,(f16)sv.y,(f16)sv.z,(f16)sv.w };
  f16x4 hp = { (f16)a.x,(f16)a.y,(f16)a.z,(f16)a.w };
  *reinterpret_cast<f16x4*>(xr + l*4)       = hs;
  *reinterpret_cast<f16x4*>(xr + 256 + l*4) = hp;
}

// ---------------- gi GEMM: D[wrow][xrow] = sum_k W_ih[wrow][k] * x[xrow][k]  (+bias) ----------------
// Writes gi in scan-friendly layout: gi[((t*16+ksl)*4+g)*16 + b'][96] f16, 96 = gate*32 + j'
#define LDAP 72
__global__ __launch_bounds__(256) void k_gemm(const f16* __restrict__ x, const f16* __restrict__ w,
                       const float* __restrict__ biasf, f16* __restrict__ gi){
  __shared__ f16 lA[128*LDAP];   // W tile   [128 wrows][64 k] padded
  __shared__ f16 lB[128*LDAP];   // x tile   [128 xrows][64 k] padded
  int by = blockIdx.x;           // wrow tile (12)
  int bx = blockIdx.y;           // xrow tile (512)
  int tid = threadIdx.x, l = tid & 63, wv = tid >> 6;
  int wm = wv >> 1, wn = wv & 1;

  f32x4 acc[4][4];
#pragma unroll
  for (int i=0;i<4;i++)
#pragma unroll
    for (int j=0;j<4;j++) acc[i][j] = (f32x4){0.f,0.f,0.f,0.f};

  for (int kt = 0; kt < 8; ++kt){
#pragma unroll
    for (int r = 0; r < 4; ++r){
      int c = tid + 256*r;            // 1024 chunks of 16B
      int row = c >> 3, o = c & 7;
      f16x8 va = *reinterpret_cast<const f16x8*>(w + (size_t)(by*128+row)*HH + kt*64 + o*8);
      f16x8 vb = *reinterpret_cast<const f16x8*>(x + (size_t)(bx*128+row)*HH + kt*64 + o*8);
      *reinterpret_cast<f16x8*>(&lA[row*LDAP + o*8]) = va;
      *reinterpret_cast<f16x8*>(&lB[row*LDAP + o*8]) = vb;
    }
    __syncthreads();
#pragma unroll
    for (int kk = 0; kk < 2; ++kk){
      f16x8 aF[4], bF[4];
#pragma unroll
      for (int mi=0;mi<4;mi++)
        aF[mi] = *reinterpret_cast<const f16x8*>(&lA[(wm*64+mi*16+(l&15))*LDAP + kk*32 + (l>>4)*8]);
#pragma unroll
      for (int ni=0;ni<4;ni++)
        bF[ni] = *reinterpret_cast<const f16x8*>(&lB[(wn*64+ni*16+(l&15))*LDAP + kk*32 + (l>>4)*8]);
#pragma unroll
      for (int mi=0;mi<4;mi++)
#pragma unroll
        for (int ni=0;ni<4;ni++)
          acc[mi][ni] = __builtin_amdgcn_mfma_f32_16x16x32_f16(aF[mi], bF[ni], acc[mi][ni], 0,0,0);
    }
    __syncthreads();
  }
  // epilogue: D m = (l>>4)*4+reg -> 4 consecutive wrows; n = l&15 -> xrow
#pragma unroll
  for (int mi=0;mi<4;mi++){
    int wrow0 = by*128 + wm*64 + mi*16 + (l>>4)*4;
    float4 bv = *reinterpret_cast<const float4*>(biasf + wrow0);
    int gate = wrow0 >> 9, j = wrow0 & 511, ksl = j >> 5, rp = gate*32 + (j&31);
#pragma unroll
    for (int ni=0;ni<4;ni++){
      int xrow = bx*128 + wn*64 + ni*16 + (l&15);
      int t = xrow >> 6, g = (xrow>>4)&3, bp = xrow & 15;
      size_t dst = ((((size_t)t*16 + ksl)*4 + g)*16 + bp)*96 + rp;
      union { u64 u; f16x4 h; } cv;
      cv.h = (f16x4){ (f16)(acc[mi][ni][0]+bv.x), (f16)(acc[mi][ni][1]+bv.y),
                      (f16)(acc[mi][ni][2]+bv.z), (f16)(acc[mi][ni][3]+bv.w) };
      *reinterpret_cast<u64*>(gi + dst) = cv.u;
    }
  }
}

// ---------------- persistent GRU scan: LDS-shared poll + chunked h layout ----------------
// 32 WGs x 256 thr (4 waves). WG (g, c): group g (16 batches), c in 0..7. Wave w owns
// j-slice jsl = c*4+w (16 j, 48 W rows in 192 pinned VGPRs). h exchange layout
// hh[t][g][jsl][b][16j], chunk = CHK=256 f16 = 512 B: producer wave's 512 B contiguous
// (full-line stores); consumer wave polls 8 contiguous chunks (4 KB, full-line loads),
// stages to LDS; 4 waves share via double-buffered LDS + one __syncthreads per step.
// Poll-the-data: hh poisoned 0xFF (finite h never produces f16 0xFFFF), u64 chunks are
// single-atomic-store all-or-nothing. ROUND-6 FIX: producer/reader chunk stride was 512,
// poll assumed 256 -> odd chunks stayed poison -> livelock. One CHK constant everywhere.
__global__ __launch_bounds__(256, 1) void k_scan(const f16* __restrict__ whh_h, const f16* __restrict__ gi,
                      const float* __restrict__ bhh, f16* __restrict__ hh){
  __shared__ f16 hb[2][16][520];                    // [parity][batch][512 j + pad 8]
  const int bid = blockIdx.x;                       // 0..31
  const int g = bid & 3, c = bid >> 2;              // group, wg-in-group
  const int tid = threadIdx.x;
  const int w = tid >> 6, l = tid & 63;
  const int lm = l & 15, lh = l >> 4;
  const int jsl = c*4 + w;                          // 0..31: this wave's 16-j slice

  // persistent A-fragments: aW[gate][kt], W row = gate*512 + jsl*16 + lm, k = kt*32 + lh*8
  f16x8 aW[3][16];
#pragma unroll
  for (int gate = 0; gate < 3; ++gate){
    const f16* wr = whh_h + ((size_t)gate*512 + jsl*16 + lm)*HH + lh*8;
#pragma unroll
    for (int kt = 0; kt < 16; ++kt)
      aW[gate][kt] = *reinterpret_cast<const f16x8*>(wr + kt*32);
  }
  // pin: make values opaque so the compiler cannot rematerialize the loads
#pragma unroll
  for (int gate = 0; gate < 3; ++gate)
#pragma unroll
    for (int kt = 0; kt < 16; ++kt)
      asm volatile("" : "+v"(aW[gate][kt]));

  const int jglob = jsl*16 + lh*4;                  // first of 4 j this lane owns
  float4 bnv = *reinterpret_cast<const float4*>(bhh + 2*HH + jglob);   // b_hh n-gate
  float bna[4] = {bnv.x, bnv.y, bnv.z, bnv.w};
  const int ksl2 = jsl >> 1, jo = (jsl & 1)*16 + lh*4;     // gi addressing
  // producer store: chunk (t,g,jsl), lane offset lm*16 + lh*4 (contiguous 512B per wave)
  // consumer poll: chunks jsl' = w*8+q, lane reads u64[l] of each 512B chunk
  const int pb = (l >> 2);                          // staged batch   (decode of u64[l])
  const int pj4 = (l & 3)*4;                        // staged j-sub

  union U64H { u64 u; f16x4 h; };
  U64H cA[3], cB[3], cC[3], ho, hn;
  ho.u = 0ull;

  // ---- t = 0 peel: h_{-1}=0, no poll; prefetch gi(1)->cB, gi(2)->cC ----
  {
    const f16* g0 = gi + ((((size_t)0*16 + ksl2)*4 + g)*16 + lm)*96;
    cA[0].u = *reinterpret_cast<const u64*>(g0 + jo);
    cA[1].u = *reinterpret_cast<const u64*>(g0 + 32 + jo);
    cA[2].u = *reinterpret_cast<const u64*>(g0 + 64 + jo);
    const f16* g1 = gi + ((((size_t)1*16 + ksl2)*4 + g)*16 + lm)*96;
    cB[0].u = *reinterpret_cast<const u64*>(g1 + jo);
    cB[1].u = *reinterpret_cast<const u64*>(g1 + 32 + jo);
    cB[2].u = *reinterpret_cast<const u64*>(g1 + 64 + jo);
    const f16* g2 = gi + ((((size_t)2*16 + ksl2)*4 + g)*16 + lm)*96;
    cC[0].u = *reinterpret_cast<const u64*>(g2 + jo);
    cC[1].u = *reinterpret_cast<const u64*>(g2 + 32 + jo);
    cC[2].u = *reinterpret_cast<const u64*>(g2 + 64 + jo);
#pragma unroll
    for (int r = 0; r < 4; ++r){
      float rg = sigm((float)cA[0].h[r]);
      float zg = sigm((float)cA[1].h[r]);
      float ng = tanh_f((float)cA[2].h[r] + rg*bna[r]);
      hn.h[r] = (f16)((1.0f - zg)*ng);
    }
    ho.u = hn.u;
    __hip_atomic_store(reinterpret_cast<u64*>(hh + ((((size_t)0*4 + g)*32 + jsl)*CHK + lm*16 + lh*4)),
                       hn.u, __ATOMIC_RELAXED, __HIP_MEMORY_SCOPE_AGENT);
  }

  // BODY(T): poll slice of h(T-1) -> LDS; barrier; prefetch gi(T+2); MFMA; gates; store h(T).
#define BODY(T, CUR, NXT2)                                                                           \
  {                                                                                                  \
    const int t_ = (T);                                                                              \
    const int par = t_ & 1;                                                                          \
    const u64* hsrc = reinterpret_cast<const u64*>(                                                  \
        hh + (((size_t)(t_-1)*4 + g)*32 + w*8)*CHK) + l;   /* chunk stride = CHK/4 = 64 u64 */       \
    u64 qq[8];                                                                                       \
    int ok;                                                                                          \
    do {                                                                                             \
      ok = 1;                                                                                        \
      _Pragma("unroll")                                                                              \
      for (int q = 0; q < 8; ++q){                                                                   \
        qq[q] = __hip_atomic_load(hsrc + (size_t)q*(CHK/4), __ATOMIC_RELAXED, __HIP_MEMORY_SCOPE_AGENT); \
        ok &= ((unsigned)qq[q] != 0xFFFFFFFFu);                                                      \
      }                                                                                              \
    } while (!__all(ok));                                                                            \
    _Pragma("unroll")                                                                                \
    for (int q = 0; q < 8; ++q)                                                                      \
      *reinterpret_cast<u64*>(&hb[par][pb][(w*8 + q)*16 + pj4]) = qq[q];                             \
    __syncthreads();                                                                                 \
    {   /* gi(t+2) prefetch: issued post-barrier, consumed 2 steps later */                          \
      const int tn_ = (t_+2 < TT) ? t_+2 : TT-1;                                                     \
      const f16* gn = gi + ((((size_t)tn_*16 + ksl2)*4 + g)*16 + lm)*96;                             \
      NXT2[0].u = *reinterpret_cast<const u64*>(gn + jo);                                            \
      NXT2[1].u = *reinterpret_cast<const u64*>(gn + 32 + jo);                                       \
      NXT2[2].u = *reinterpret_cast<const u64*>(gn + 64 + jo);                                       \
    }                                                                                                \
    f32x4 aR = (f32x4){0.f,0.f,0.f,0.f};                                                             \
    f32x4 aZ = (f32x4){0.f,0.f,0.f,0.f};                                                             \
    f32x4 aN = (f32x4){0.f,0.f,0.f,0.f};                                                             \
    _Pragma("unroll")                                                                                \
    for (int kt = 0; kt < 16; ++kt){                                                                 \
      f16x8 bF = *reinterpret_cast<const f16x8*>(&hb[par][lm][kt*32 + lh*8]);                        \
      aR = __builtin_amdgcn_mfma_f32_16x16x32_f16(aW[0][kt], bF, aR, 0,0,0);                         \
      aZ = __builtin_amdgcn_mfma_f32_16x16x32_f16(aW[1][kt], bF, aZ, 0,0,0);                         \
      aN = __builtin_amdgcn_mfma_f32_16x16x32_f16(aW[2][kt], bF, aN, 0,0,0);                         \
    }                                                                                                \
    _Pragma("unroll")                                                                                \
    for (int r = 0; r < 4; ++r){                                                                     \
      float rg = sigm((float)CUR[0].h[r] + aR[r]);                                                   \
      float zg = sigm((float)CUR[1].h[r] + aZ[r]);                                                   \
      float ng = tanh_f((float)CUR[2].h[r] + rg*(aN[r] + bna[r]));                                   \
      hn.h[r] = (f16)((1.0f - zg)*ng + zg*(float)ho.h[r]);                                           \
    }                                                                                                \
    ho.u = hn.u;                                                                                     \
    __hip_atomic_store(reinterpret_cast<u64*>(hh + ((((size_t)t_*4 + g)*32 + jsl)*CHK + lm*16 + lh*4)),\
                       hn.u, __ATOMIC_RELAXED, __HIP_MEMORY_SCOPE_AGENT);                            \
  }

  // t = 1..1023 in 341 triples, 3-buffer gi rotation
  for (int t = 1; t < TT; t += 3){
    BODY(t,   cB, cA)
    BODY(t+1, cC, cB)
    BODY(t+2, cA, cC)
  }
#undef BODY
}

// ---------------- rewards = sigmoid(h @ W_t + b_t) (chunked hh layout, stride CHK) ----------------
__global__ void k_reward(const f16* __restrict__ hh, const float* __restrict__ wt,
                         const float* __restrict__ bt, float* __restrict__ out){
  int wv = threadIdx.x >> 6, l = threadIdx.x & 63;
  int idx = blockIdx.x*4 + wv;          // idx = b*1024 + t (output order [B][T])
  int b = idx >> 10, t = idx & 1023;
  int g = b >> 4, bl = b & 15;
  // element j of h(b,t) lives at hh[((t*4+g)*32 + (j>>4))*CHK + bl*16 + (j&15)]
  const f16* hr = hh + (((size_t)t*4 + g)*32 + (l >> 1))*CHK + bl*16 + (l & 1)*8;
  f16x8 hv = *reinterpret_cast<const f16x8*>(hr);      // j = l*8 .. l*8+7
  float4 w0 = *reinterpret_cast<const float4*>(wt + l*8);
  float4 w1 = *reinterpret_cast<const float4*>(wt + l*8 + 4);
  float sum = (float)hv[0]*w0.x + (float)hv[1]*w0.y + (float)hv[2]*w0.z + (float)hv[3]*w0.w
            + (float)hv[4]*w1.x + (float)hv[5]*w1.y + (float)hv[6]*w1.z + (float)hv[7]*w1.w;
#pragma unroll
  for (int m=32;m>=1;m>>=1) sum += __shfl_xor(sum, m);
  if (l==0) out[idx] = sigm(sum + bt[0]);
}

extern "C" void kernel_launch(void* const* d_in, const int* in_sizes, int n_in,
                              void* d_out, int out_size, void* d_ws, size_t ws_size,
                              hipStream_t stream) {
  const float* s   = (const float*)d_in[0];
  const float* p   = (const float*)d_in[1];
  const float* wih = (const float*)d_in[2];
  const float* whh = (const float*)d_in[3];
  const float* bih = (const float*)d_in[4];
  const float* bhh = (const float*)d_in[5];
  const float* wt  = (const float*)d_in[6];
  const float* bt  = (const float*)d_in[7];
  float* out = (float*)d_out;

  char* ws = (char*)d_ws;
  size_t o = 0;
  auto take = [&](size_t bytes)->char*{ char* r = ws + o; o = (o + bytes + 255) & ~(size_t)255; return r; };
  f16*      x_h   = (f16*)   take((size_t)TT*BB*HH*2);       // 67 MB
  f16*      wih_h = (f16*)   take((size_t)G3*HH*2);
  f16*      whh_h = (f16*)   take((size_t)G3*HH*2);
  float*    biasf = (float*) take((size_t)G3*4);
  f16*      gi_s  = (f16*)   take((size_t)TT*BB*G3*2);       // 201 MB
  f16*      hh    = (f16*)   take((size_t)TT*BB*HH*2);       // 67 MB, chunked layout (CHK f16/chunk)
  (void)ws_size; (void)in_sizes; (void)n_in; (void)out_size;

  hipMemsetAsync(hh, 0xFF, (size_t)TT*BB*HH*2, stream);      // poison: poll-the-data sentinel
  k_prep  <<<3072, 256, 0, stream>>>(wih, whh, bih, bhh, wih_h, whh_h, biasf);
  k_buildx<<<TT*BB, 64, 0, stream>>>(s, p, x_h);
  k_gemm  <<<dim3(12, 512), 256, 0, stream>>>(x_h, wih_h, biasf, gi_s);
  k_scan  <<<32, 256, 0, stream>>>(whh_h, gi_s, bhh, hh);
  k_reward<<<TT*BB/4, 256, 0, stream>>>(hh, wt, bt, out);
}